// Round 6
// baseline (185.950 us; speedup 1.0000x reference)
//
#include <hip/hip_runtime.h>
#include <hip/hip_bf16.h>

// Problem constants
#define BB     8
#define HH     16
#define QLEN   256
#define DH     128
#define BSZ    16
#define MAXB   256
#define KT     64            // kv tile
#define BHQ    (BB*HH*QLEN)  // 32768 rows
#define VROW   144           // padded V^T row stride in bytes (64*2 + 16)

typedef __attribute__((ext_vector_type(8))) short bf16x8;
typedef __attribute__((ext_vector_type(4))) short bf16x4;
typedef __attribute__((ext_vector_type(4))) float f32x4;

__device__ __forceinline__ unsigned pk2(float a, float b) {   // a -> low bf16, b -> high
  union { __hip_bfloat162 h; unsigned u; } c;
  c.h = __float22bfloat162_rn(make_float2(a, b));
  return c.u;
}

__device__ __forceinline__ f32x4 mfma16(bf16x4 a, bf16x4 b, f32x4 c) {
#if __has_builtin(__builtin_amdgcn_mfma_f32_16x16x16bf16_1k)
  return __builtin_amdgcn_mfma_f32_16x16x16bf16_1k(a, b, c, 0, 0, 0);
#else
  asm volatile("v_mfma_f32_16x16x16_bf16 %0, %1, %2, %0" : "+v"(c) : "v"(a), "v"(b));
  return c;
#endif
}

// Block = (bh, c): 512 thr / 8 waves; wave owns 32 q rows (2 M-tiles of 16).
// All 256 q rows in one block -> each staged KV byte feeds full Q via LDS.
// Swapped-QK^T flash attention:
//   S^T = mfma_16x16x32(A=K[kv][d], B=Q^T[d][q])  -> lane q=ll, kv=mt*16+lg*4+r
//   softmax lane-local (+2 shfl_xor), P packed in-register (cvt_pk)
//   O^T = mfma_16x16x16(A=V^T[d][kv16], B=P^T[kv16][q]) -> lane q=ll, d=nj*16+lg*4+r
// LDS double-buffered; ONE barrier per tile; tile t+1 global loads issued
// AFTER the barrier, converted + written at the top of iteration t+1.
// Defer-max (T13): skip acc rescale while __all(mx - m <= 8)  (P bounded 2^8).
// K LDS: [64][128] bf16 row-major, XOR swizzle ((row&7)<<4) on 16B units.
// V LDS: [128 d][64 kv] bf16 transposed, row stride 144 B, kv-offset XOR ((d>>2)&15)<<3.
__launch_bounds__(512, 2)
__global__ void paged_attn_kernel(const float* __restrict__ qg,
                                  const float* __restrict__ kc,
                                  const float* __restrict__ vc,
                                  const int* __restrict__ bt,
                                  const int* __restrict__ sl,
                                  float* __restrict__ opart,   // [nkv][BHQ][DH] (or out if nkv==1)
                                  float* __restrict__ mpart,   // [nkv][BHQ]
                                  float* __restrict__ lpart,   // [nkv][BHQ]
                                  int nkv) {
  __shared__ __align__(16) char kls[2][KT * DH * 2];   // 2 x 16 KiB
  __shared__ __align__(16) char vls[2][DH * VROW];     // 2 x 18 KiB
  __shared__ int btab[MAXB];                           // 1 KiB

  const int tid  = threadIdx.x;
  const int wave = tid >> 6;    // 0..7
  const int lane = tid & 63;
  const int lg   = lane >> 4;   // 16-lane group 0..3
  const int ll   = lane & 15;

  const int bid = blockIdx.x;
  const int c   = bid % nkv;
  const int bh  = bid / nkv;
  const int b   = bh >> 4;      // H = 16
  const int h   = bh & 15;

  const int seq = sl[b];
  const int nt  = (seq + KT - 1) / KT;
  const int per = (nt + nkv - 1) / nkv;
  const int t0  = c * per;
  const int t1  = (t0 + per < nt) ? (t0 + per) : nt;

  if (tid < MAXB) btab[tid] = bt[b * MAXB + tid];
  __syncthreads();  // btab visible

  // ---- prefetch registers for one tile ----
  float4 kreg[2][2];   // K slot i: rows (i*512+tid)>>4, 16B chunk (i*512+tid)&15
  float4 vreg[2][2];   // V slot i: kv pair (i*512+tid)>>5, float4 col (i*512+tid)&31

#define ISSUE_LOADS(KV0)                                                        \
  {                                                                             \
    _Pragma("unroll")                                                           \
    for (int i = 0; i < 2; ++i) {                                               \
      const int slot = i * 512 + tid;                                           \
      const int row = slot >> 4, c16 = slot & 15;                               \
      const int kv = (KV0) + row;                                               \
      const int phys = btab[kv >> 4];                                           \
      const size_t gb = (((size_t)phys * HH + h) * BSZ + (kv & 15)) * DH + c16 * 8; \
      kreg[i][0] = *(const float4*)(kc + gb);                                   \
      kreg[i][1] = *(const float4*)(kc + gb + 4);                               \
    }                                                                           \
    _Pragma("unroll")                                                           \
    for (int i = 0; i < 2; ++i) {                                               \
      const int slot = i * 512 + tid;                                           \
      const int kvp = slot >> 5, col4 = slot & 31;                              \
      const int kv = (KV0) + kvp * 2;                                           \
      const int phys = btab[kv >> 4];                                           \
      const size_t gb = (((size_t)phys * HH + h) * BSZ + (kv & 15)) * DH + col4 * 4; \
      vreg[i][0] = *(const float4*)(vc + gb);                                   \
      vreg[i][1] = *(const float4*)(vc + gb + DH);                              \
    }                                                                           \
  }

  if (t0 < t1) ISSUE_LOADS(t0 * KT)   // prologue: tile t0 in flight

  // ---- Q fragments (B-operand of S^T), scale*log2(e) folded in ----
  const float qscale = 0.08838834764831845f * 1.4426950408889634f;
  const int qbase = wave * 32;
  bf16x8 qf[2][4];
#pragma unroll
  for (int mi = 0; mi < 2; ++mi) {
    const float* qr = qg + ((size_t)bh * QLEN + qbase + mi * 16 + ll) * DH;
#pragma unroll
    for (int ks = 0; ks < 4; ++ks) {
      const float4 a  = *(const float4*)(qr + ks * 32 + lg * 8);
      const float4 bv = *(const float4*)(qr + ks * 32 + lg * 8 + 4);
      union { bf16x8 v; unsigned u[4]; } w;
      w.u[0] = pk2(a.x * qscale,  a.y * qscale);
      w.u[1] = pk2(a.z * qscale,  a.w * qscale);
      w.u[2] = pk2(bv.x * qscale, bv.y * qscale);
      w.u[3] = pk2(bv.z * qscale, bv.w * qscale);
      qf[mi][ks] = w.v;
    }
  }

  f32x4 accT[2][8];    // O^T: lane q = qbase+mi*16+ll, d = nj*16 + lg*4 + r
#pragma unroll
  for (int mi = 0; mi < 2; ++mi)
#pragma unroll
    for (int nj = 0; nj < 8; ++nj) accT[mi][nj] = (f32x4){0.f, 0.f, 0.f, 0.f};
  float mrow[2] = {-1e30f, -1e30f}, lrow[2] = {0.f, 0.f};

  for (int t = t0; t < t1; ++t) {
    const int kv0 = t * KT;
    const int bb  = t & 1;

    // ---- convert prefetched fp32 -> bf16, write LDS buf bb (vmcnt waits here) ----
#pragma unroll
    for (int i = 0; i < 2; ++i) {
      const int slot = i * 512 + tid;
      const int row = slot >> 4, c16 = slot & 15;
      union { uint4 u4; unsigned u[4]; } w;
      w.u[0] = pk2(kreg[i][0].x, kreg[i][0].y);
      w.u[1] = pk2(kreg[i][0].z, kreg[i][0].w);
      w.u[2] = pk2(kreg[i][1].x, kreg[i][1].y);
      w.u[3] = pk2(kreg[i][1].z, kreg[i][1].w);
      const int kb = (row * 256 + c16 * 16) ^ ((row & 7) << 4);
      *(uint4*)(kls[bb] + kb) = w.u4;
    }
#pragma unroll
    for (int i = 0; i < 2; ++i) {
      const int slot = i * 512 + tid;
      const int kvp = slot >> 5, col4 = slot & 31;
      const float* aa = (const float*)&vreg[i][0];
      const float* bp = (const float*)&vreg[i][1];
#pragma unroll
      for (int jj = 0; jj < 4; ++jj) {
        const int d  = col4 * 4 + jj;
        const int xo = ((d >> 2) & 15) << 3;
        *(unsigned*)(vls[bb] + d * VROW + ((kvp * 4) ^ xo)) = pk2(aa[jj], bp[jj]);
      }
    }

    __syncthreads();  // buf bb ready; all waves done computing tile t-1

    // ---- issue tile t+1 loads AFTER barrier (not drained by it) ----
    if (t + 1 < t1) ISSUE_LOADS((t + 1) * KT)

    // ---- S^T = K · Q^T ----
    f32x4 s[2][4];
    __builtin_amdgcn_s_setprio(1);
#pragma unroll
    for (int mt = 0; mt < 4; ++mt) {
      const int krow  = mt * 16 + ll;
      const int kbase = krow * 256;
      const int ksw   = (krow & 7) << 4;
      bf16x8 kf[4];
#pragma unroll
      for (int ks = 0; ks < 4; ++ks)
        kf[ks] = *(const bf16x8*)(kls[bb] + ((kbase + ks * 64 + lg * 16) ^ ksw));
      s[0][mt] = (f32x4){0.f, 0.f, 0.f, 0.f};
      s[1][mt] = (f32x4){0.f, 0.f, 0.f, 0.f};
#pragma unroll
      for (int ks = 0; ks < 4; ++ks)
#pragma unroll
        for (int mi = 0; mi < 2; ++mi)
          s[mi][mt] = __builtin_amdgcn_mfma_f32_16x16x32_bf16(kf[ks], qf[mi][ks], s[mi][mt], 0, 0, 0);
    }
    __builtin_amdgcn_s_setprio(0);

    // ---- online softmax: lane owns q-row, 16 scores kv = mt*16+lg*4+r ----
    const bool tail = (kv0 + KT > seq);
    bf16x4 pb[2][4];
#pragma unroll
    for (int mi = 0; mi < 2; ++mi) {
      if (tail) {
#pragma unroll
        for (int mt = 0; mt < 4; ++mt)
#pragma unroll
          for (int r = 0; r < 4; ++r) {
            const int kvg = kv0 + mt * 16 + lg * 4 + r;
            if (kvg >= seq) s[mi][mt][r] = -1e30f;
          }
      }
      float mx = s[mi][0][0];
#pragma unroll
      for (int mt = 0; mt < 4; ++mt)
#pragma unroll
        for (int r = 0; r < 4; ++r) mx = fmaxf(mx, s[mi][mt][r]);
      mx = fmaxf(mx, __shfl_xor(mx, 16));
      mx = fmaxf(mx, __shfl_xor(mx, 32));
      // T13 defer-max: rescale only when some lane's max grew past m+8.
      if (!__all(mx - mrow[mi] <= 8.0f)) {
        const float mnew  = fmaxf(mrow[mi], mx);
        const float alpha = exp2f(mrow[mi] - mnew);
        mrow[mi] = mnew;
        lrow[mi] *= alpha;
#pragma unroll
        for (int nj = 0; nj < 8; ++nj) {
          accT[mi][nj][0] *= alpha; accT[mi][nj][1] *= alpha;
          accT[mi][nj][2] *= alpha; accT[mi][nj][3] *= alpha;
        }
      }
      float rs = 0.f;
#pragma unroll
      for (int mt = 0; mt < 4; ++mt)
#pragma unroll
        for (int r = 0; r < 4; ++r) {
          s[mi][mt][r] = exp2f(s[mi][mt][r] - mrow[mi]);   // bounded by 2^8
          rs += s[mi][mt][r];
        }
      rs += __shfl_xor(rs, 16);
      rs += __shfl_xor(rs, 32);
      lrow[mi] += rs;
#pragma unroll
      for (int mt = 0; mt < 4; ++mt) {
        union { bf16x4 v; unsigned u[2]; } w;
        w.u[0] = pk2(s[mi][mt][0], s[mi][mt][1]);
        w.u[1] = pk2(s[mi][mt][2], s[mi][mt][3]);
        pb[mi][mt] = w.v;
      }
    }

    // ---- O^T += V^T · P^T ----
    __builtin_amdgcn_s_setprio(1);
#pragma unroll
    for (int nj = 0; nj < 8; ++nj) {
      const int d  = nj * 16 + ll;
      const int xo = ((d >> 2) & 15) << 3;
      const char* vb = vls[bb] + d * VROW;
#pragma unroll
      for (int mt = 0; mt < 4; ++mt) {
        const bf16x4 va = *(const bf16x4*)(vb + ((lg * 8 + mt * 32) ^ xo));
#pragma unroll
        for (int mi = 0; mi < 2; ++mi)
          accT[mi][nj] = mfma16(va, pb[mi][mt], accT[mi][nj]);
      }
    }
    __builtin_amdgcn_s_setprio(0);
  }

  // ---- epilogue: lane writes q-row, d = nj*16+lg*4 .. +3 (float4) ----
#pragma unroll
  for (int mi = 0; mi < 2; ++mi) {
    const int grow = bh * QLEN + qbase + mi * 16 + ll;
    if (nkv == 1) {
      const float inv = 1.0f / lrow[mi];
      float* orow = opart + (size_t)grow * DH;
#pragma unroll
      for (int nj = 0; nj < 8; ++nj) {
        f32x4 v = accT[mi][nj];
        v[0] *= inv; v[1] *= inv; v[2] *= inv; v[3] *= inv;
        *(f32x4*)(orow + nj * 16 + lg * 4) = v;
      }
    } else {
      float* orow = opart + ((size_t)c * BHQ + grow) * DH;
#pragma unroll
      for (int nj = 0; nj < 8; ++nj)
        *(f32x4*)(orow + nj * 16 + lg * 4) = accT[mi][nj];   // unnormalized
      if (lg == 0) {
        mpart[c * BHQ + grow] = mrow[mi];
        lpart[c * BHQ + grow] = lrow[mi];
      }
    }
  }
}

__global__ void combine_kernel(const float* __restrict__ op,
                               const float* __restrict__ mp,
                               const float* __restrict__ lp,
                               float* __restrict__ out, int nkv) {
  const int idx = blockIdx.x * 256 + threadIdx.x;  // float4 index over BHQ*DH/4
  const int row = idx >> 5;                        // 32 float4 per row
  float M = -1e30f;
  for (int cc = 0; cc < nkv; ++cc) M = fmaxf(M, mp[cc * BHQ + row]);
  float den = 0.f;
  float4 o = make_float4(0.f, 0.f, 0.f, 0.f);
  for (int cc = 0; cc < nkv; ++cc) {
    const float w = exp2f(mp[cc * BHQ + row] - M);
    den += lp[cc * BHQ + row] * w;
    const float4 v = ((const float4*)op)[(size_t)cc * (BHQ * (DH / 4)) + idx];
    o.x += w * v.x; o.y += w * v.y; o.z += w * v.z; o.w += w * v.w;
  }
  const float inv = 1.0f / den;
  ((float4*)out)[idx] = make_float4(o.x * inv, o.y * inv, o.z * inv, o.w * inv);
}

extern "C" void kernel_launch(void* const* d_in, const int* in_sizes, int n_in,
                              void* d_out, int out_size, void* d_ws, size_t ws_size,
                              hipStream_t stream) {
  const float* q  = (const float*)d_in[0];
  const float* kc = (const float*)d_in[1];
  const float* vc = (const float*)d_in[2];
  const int* bt   = (const int*)d_in[3];
  const int* sl   = (const int*)d_in[4];
  float* out = (float*)d_out;

  const size_t perchunk = (size_t)BHQ * DH * sizeof(float) + (size_t)BHQ * 2 * sizeof(float);
  int nkv = 1;
  if (ws_size >= 8 * perchunk) nkv = 8;        // 1024 blocks -> refill smoothing
  else if (ws_size >= 4 * perchunk) nkv = 4;
  else if (ws_size >= 2 * perchunk) nkv = 2;

  float* op = (nkv == 1) ? out : (float*)d_ws;
  float* mp = (float*)d_ws + (size_t)nkv * BHQ * DH;
  float* lp = mp + (size_t)nkv * BHQ;

  paged_attn_kernel<<<dim3(BB * HH * nkv), dim3(512), 0, stream>>>(q, kc, vc, bt, sl, op, mp, lp, nkv);
  if (nkv > 1)
    combine_kernel<<<dim3(BHQ * DH / 4 / 256), dim3(256), 0, stream>>>(op, mp, lp, out, nkv);
}

// Round 7
// 161.742 us; speedup vs baseline: 1.1497x; 1.1497x over previous
//
#include <hip/hip_runtime.h>
#include <hip/hip_bf16.h>

// Problem constants
#define BB     8
#define HH     16
#define QLEN   256
#define DH     128
#define BSZ    16
#define MAXB   256
#define KT     64            // kv tile
#define CHK    12            // target tiles per chunk (load balance)
#define BHQ    (BB*HH*QLEN)  // 32768 rows
#define VROW   144           // padded V^T row stride in bytes (64*2 + 16)

typedef __attribute__((ext_vector_type(8))) short bf16x8;
typedef __attribute__((ext_vector_type(4))) short bf16x4;
typedef __attribute__((ext_vector_type(4))) float f32x4;

__device__ __forceinline__ unsigned pk2(float a, float b) {   // a -> low bf16, b -> high
  union { __hip_bfloat162 h; unsigned u; } c;
  c.h = __float22bfloat162_rn(make_float2(a, b));
  return c.u;
}

__device__ __forceinline__ float fexp2(float x) {
#if __has_builtin(__builtin_amdgcn_exp2f)
  return __builtin_amdgcn_exp2f(x);
#else
  return exp2f(x);
#endif
}

__device__ __forceinline__ f32x4 mfma16(bf16x4 a, bf16x4 b, f32x4 c) {
#if __has_builtin(__builtin_amdgcn_mfma_f32_16x16x16bf16_1k)
  return __builtin_amdgcn_mfma_f32_16x16x16bf16_1k(a, b, c, 0, 0, 0);
#else
  asm volatile("v_mfma_f32_16x16x16_bf16 %0, %1, %2, %0" : "+v"(c) : "v"(a), "v"(b));
  return c;
#endif
}

// chunk count for a sequence with nt tiles, given workspace capacity nc
__device__ __forceinline__ int chunks_of(int nt, int nc) {
  return (nc >= 6) ? min(nc, (nt + CHK - 1) / CHK) : nc;
}

// Block = (bh, c): 512 thr / 8 waves; wave owns 32 q rows (2 M-tiles of 16).
// All 256 q rows in one block -> each staged KV byte feeds full Q via LDS.
// Equal-tile chunking: cb = ceil(nt/12) chunks of ~11-12 tiles each -> all
// blocks do similar work (fixed per-seq nkv split had 8..16-tile spread ->
// ~30% makespan tail at 2 resident blocks/CU). Blocks with c >= cb exit.
// Swapped-QK^T flash attention:
//   S^T = mfma_16x16x32(A=K[kv][d], B=Q^T[d][q])  -> lane q=ll, kv=mt*16+lg*4+r
//   softmax lane-local (+2 shfl_xor), P packed in-register (cvt_pk)
//   O^T = mfma_16x16x16(A=V^T[d][kv16], B=P^T[kv16][q]) -> lane q=ll, d=nj*16+lg*4+r
// LDS double-buffered; ONE barrier per tile; tile t+1 global loads issued
// AFTER the barrier, converted + written at the top of iteration t+1.
// Defer-max (T13): skip acc rescale while __all(mx - m <= 8)  (P bounded 2^8).
// K LDS: [64][128] bf16 row-major, XOR swizzle ((row&7)<<4) on 16B units.
// V LDS: [128 d][64 kv] bf16 transposed, row stride 144 B, kv-offset XOR ((d>>2)&15)<<3.
__launch_bounds__(512, 2)
__global__ void paged_attn_kernel(const float* __restrict__ qg,
                                  const float* __restrict__ kc,
                                  const float* __restrict__ vc,
                                  const int* __restrict__ bt,
                                  const int* __restrict__ sl,
                                  float* __restrict__ opart,   // [nc][BHQ][DH] (or out if nc==1)
                                  float* __restrict__ mpart,   // [nc][BHQ]
                                  float* __restrict__ lpart,   // [nc][BHQ]
                                  int nc) {
  __shared__ __align__(16) char kls[2][KT * DH * 2];   // 2 x 16 KiB
  __shared__ __align__(16) char vls[2][DH * VROW];     // 2 x 18 KiB
  __shared__ int btab[MAXB];                           // 1 KiB

  const int tid  = threadIdx.x;
  const int wave = tid >> 6;    // 0..7
  const int lane = tid & 63;
  const int lg   = lane >> 4;   // 16-lane group 0..3
  const int ll   = lane & 15;

  const int bid = blockIdx.x;
  const int c   = bid % nc;
  const int bh  = bid / nc;
  const int b   = bh >> 4;      // H = 16
  const int h   = bh & 15;

  const int seq = sl[b];
  const int nt  = (seq + KT - 1) / KT;
  const int cb  = chunks_of(nt, nc);
  const int per = (nt + cb - 1) / cb;
  const int t0  = c * per;
  const int t1  = (t0 + per < nt) ? (t0 + per) : nt;

  if (tid < MAXB) btab[tid] = bt[b * MAXB + tid];
  __syncthreads();  // btab visible
  if (c >= cb) return;   // surplus block (workspace sized for nc >= cb)

  // ---- prefetch registers for one tile ----
  float4 kreg[2][2];   // K slot i: rows (i*512+tid)>>4, 16B chunk (i*512+tid)&15
  float4 vreg[2][2];   // V slot i: kv pair (i*512+tid)>>5, float4 col (i*512+tid)&31

#define ISSUE_LOADS(KV0)                                                        \
  {                                                                             \
    _Pragma("unroll")                                                           \
    for (int i = 0; i < 2; ++i) {                                               \
      const int slot = i * 512 + tid;                                           \
      const int row = slot >> 4, c16 = slot & 15;                               \
      const int kv = (KV0) + row;                                               \
      const int phys = btab[kv >> 4];                                           \
      const size_t gb = (((size_t)phys * HH + h) * BSZ + (kv & 15)) * DH + c16 * 8; \
      kreg[i][0] = *(const float4*)(kc + gb);                                   \
      kreg[i][1] = *(const float4*)(kc + gb + 4);                               \
    }                                                                           \
    _Pragma("unroll")                                                           \
    for (int i = 0; i < 2; ++i) {                                               \
      const int slot = i * 512 + tid;                                           \
      const int kvp = slot >> 5, col4 = slot & 31;                              \
      const int kv = (KV0) + kvp * 2;                                           \
      const int phys = btab[kv >> 4];                                           \
      const size_t gb = (((size_t)phys * HH + h) * BSZ + (kv & 15)) * DH + col4 * 4; \
      vreg[i][0] = *(const float4*)(vc + gb);                                   \
      vreg[i][1] = *(const float4*)(vc + gb + DH);                              \
    }                                                                           \
  }

  ISSUE_LOADS(t0 * KT)   // prologue: tile t0 in flight

  // ---- Q fragments (B-operand of S^T), scale*log2(e) folded in ----
  const float qscale = 0.08838834764831845f * 1.4426950408889634f;
  const int qbase = wave * 32;
  bf16x8 qf[2][4];
#pragma unroll
  for (int mi = 0; mi < 2; ++mi) {
    const float* qr = qg + ((size_t)bh * QLEN + qbase + mi * 16 + ll) * DH;
#pragma unroll
    for (int ks = 0; ks < 4; ++ks) {
      const float4 a  = *(const float4*)(qr + ks * 32 + lg * 8);
      const float4 bv = *(const float4*)(qr + ks * 32 + lg * 8 + 4);
      union { bf16x8 v; unsigned u[4]; } w;
      w.u[0] = pk2(a.x * qscale,  a.y * qscale);
      w.u[1] = pk2(a.z * qscale,  a.w * qscale);
      w.u[2] = pk2(bv.x * qscale, bv.y * qscale);
      w.u[3] = pk2(bv.z * qscale, bv.w * qscale);
      qf[mi][ks] = w.v;
    }
  }

  f32x4 accT[2][8];    // O^T: lane q = qbase+mi*16+ll, d = nj*16 + lg*4 + r
#pragma unroll
  for (int mi = 0; mi < 2; ++mi)
#pragma unroll
    for (int nj = 0; nj < 8; ++nj) accT[mi][nj] = (f32x4){0.f, 0.f, 0.f, 0.f};
  float mrow[2] = {-1e30f, -1e30f}, lrow[2] = {0.f, 0.f};

  for (int t = t0; t < t1; ++t) {
    const int kv0 = t * KT;
    const int bb  = t & 1;

    // ---- convert prefetched fp32 -> bf16, write LDS buf bb (vmcnt waits here) ----
#pragma unroll
    for (int i = 0; i < 2; ++i) {
      const int slot = i * 512 + tid;
      const int row = slot >> 4, c16 = slot & 15;
      union { uint4 u4; unsigned u[4]; } w;
      w.u[0] = pk2(kreg[i][0].x, kreg[i][0].y);
      w.u[1] = pk2(kreg[i][0].z, kreg[i][0].w);
      w.u[2] = pk2(kreg[i][1].x, kreg[i][1].y);
      w.u[3] = pk2(kreg[i][1].z, kreg[i][1].w);
      const int kb = (row * 256 + c16 * 16) ^ ((row & 7) << 4);
      *(uint4*)(kls[bb] + kb) = w.u4;
    }
#pragma unroll
    for (int i = 0; i < 2; ++i) {
      const int slot = i * 512 + tid;
      const int kvp = slot >> 5, col4 = slot & 31;
      const float* aa = (const float*)&vreg[i][0];
      const float* bp = (const float*)&vreg[i][1];
#pragma unroll
      for (int jj = 0; jj < 4; ++jj) {
        const int d  = col4 * 4 + jj;
        const int xo = ((d >> 2) & 15) << 3;
        *(unsigned*)(vls[bb] + d * VROW + ((kvp * 4) ^ xo)) = pk2(aa[jj], bp[jj]);
      }
    }

    __syncthreads();  // buf bb ready; all waves done computing tile t-1

    // ---- issue tile t+1 loads AFTER barrier (not drained by it) ----
    if (t + 1 < t1) ISSUE_LOADS((t + 1) * KT)

    // ---- S^T = K · Q^T ----
    f32x4 s[2][4];
    __builtin_amdgcn_s_setprio(1);
#pragma unroll
    for (int mt = 0; mt < 4; ++mt) {
      const int krow  = mt * 16 + ll;
      const int kbase = krow * 256;
      const int ksw   = (krow & 7) << 4;
      bf16x8 kf[4];
#pragma unroll
      for (int ks = 0; ks < 4; ++ks)
        kf[ks] = *(const bf16x8*)(kls[bb] + ((kbase + ks * 64 + lg * 16) ^ ksw));
      s[0][mt] = (f32x4){0.f, 0.f, 0.f, 0.f};
      s[1][mt] = (f32x4){0.f, 0.f, 0.f, 0.f};
#pragma unroll
      for (int ks = 0; ks < 4; ++ks)
#pragma unroll
        for (int mi = 0; mi < 2; ++mi)
          s[mi][mt] = __builtin_amdgcn_mfma_f32_16x16x32_bf16(kf[ks], qf[mi][ks], s[mi][mt], 0, 0, 0);
    }
    __builtin_amdgcn_s_setprio(0);

    // ---- online softmax: lane owns q-row, 16 scores kv = mt*16+lg*4+r ----
    const bool tail = (kv0 + KT > seq);
    bf16x4 pb[2][4];
#pragma unroll
    for (int mi = 0; mi < 2; ++mi) {
      if (tail) {
#pragma unroll
        for (int mt = 0; mt < 4; ++mt)
#pragma unroll
          for (int r = 0; r < 4; ++r) {
            const int kvg = kv0 + mt * 16 + lg * 4 + r;
            if (kvg >= seq) s[mi][mt][r] = -1e30f;
          }
      }
      float mx = s[mi][0][0];
#pragma unroll
      for (int mt = 0; mt < 4; ++mt)
#pragma unroll
        for (int r = 0; r < 4; ++r) mx = fmaxf(mx, s[mi][mt][r]);
      mx = fmaxf(mx, __shfl_xor(mx, 16));
      mx = fmaxf(mx, __shfl_xor(mx, 32));
      // T13 defer-max: rescale only when some lane's max grew past m+8.
      if (!__all(mx - mrow[mi] <= 8.0f)) {
        const float mnew  = fmaxf(mrow[mi], mx);
        const float alpha = fexp2(mrow[mi] - mnew);
        mrow[mi] = mnew;
        lrow[mi] *= alpha;
#pragma unroll
        for (int nj = 0; nj < 8; ++nj) {
          accT[mi][nj][0] *= alpha; accT[mi][nj][1] *= alpha;
          accT[mi][nj][2] *= alpha; accT[mi][nj][3] *= alpha;
        }
      }
      float rs = 0.f;
#pragma unroll
      for (int mt = 0; mt < 4; ++mt)
#pragma unroll
        for (int r = 0; r < 4; ++r) {
          s[mi][mt][r] = fexp2(s[mi][mt][r] - mrow[mi]);   // bounded by 2^8
          rs += s[mi][mt][r];
        }
      rs += __shfl_xor(rs, 16);
      rs += __shfl_xor(rs, 32);
      lrow[mi] += rs;
#pragma unroll
      for (int mt = 0; mt < 4; ++mt) {
        union { bf16x4 v; unsigned u[2]; } w;
        w.u[0] = pk2(s[mi][mt][0], s[mi][mt][1]);
        w.u[1] = pk2(s[mi][mt][2], s[mi][mt][3]);
        pb[mi][mt] = w.v;
      }
    }

    // ---- O^T += V^T · P^T ----
    __builtin_amdgcn_s_setprio(1);
#pragma unroll
    for (int nj = 0; nj < 8; ++nj) {
      const int d  = nj * 16 + ll;
      const int xo = ((d >> 2) & 15) << 3;
      const char* vb = vls[bb] + d * VROW;
#pragma unroll
      for (int mt = 0; mt < 4; ++mt) {
        const bf16x4 va = *(const bf16x4*)(vb + ((lg * 8 + mt * 32) ^ xo));
#pragma unroll
        for (int mi = 0; mi < 2; ++mi)
          accT[mi][nj] = mfma16(va, pb[mi][mt], accT[mi][nj]);
      }
    }
    __builtin_amdgcn_s_setprio(0);
  }

  // ---- epilogue: lane writes q-row, d = nj*16+lg*4 .. +3 (float4) ----
#pragma unroll
  for (int mi = 0; mi < 2; ++mi) {
    const int grow = bh * QLEN + qbase + mi * 16 + ll;
    if (nc == 1) {
      const float inv = 1.0f / lrow[mi];
      float* orow = opart + (size_t)grow * DH;
#pragma unroll
      for (int nj = 0; nj < 8; ++nj) {
        f32x4 v = accT[mi][nj];
        v[0] *= inv; v[1] *= inv; v[2] *= inv; v[3] *= inv;
        *(f32x4*)(orow + nj * 16 + lg * 4) = v;
      }
    } else {
      float* orow = opart + ((size_t)c * BHQ + grow) * DH;
#pragma unroll
      for (int nj = 0; nj < 8; ++nj)
        *(f32x4*)(orow + nj * 16 + lg * 4) = accT[mi][nj];   // unnormalized
      if (lg == 0) {
        mpart[c * BHQ + grow] = mrow[mi];
        lpart[c * BHQ + grow] = lrow[mi];
      }
    }
  }
}

__global__ void combine_kernel(const float* __restrict__ op,
                               const float* __restrict__ mp,
                               const float* __restrict__ lp,
                               const int* __restrict__ sl,
                               float* __restrict__ out, int nc) {
  const int idx = blockIdx.x * 256 + threadIdx.x;  // float4 index over BHQ*DH/4
  const int row = idx >> 5;                        // 32 float4 per row
  const int b   = row >> 12;                       // row / (16*256)
  const int seq = sl[b];
  const int nt  = (seq + KT - 1) / KT;
  const int cb  = chunks_of(nt, nc);
  float M = -1e30f;
  for (int cc = 0; cc < cb; ++cc) M = fmaxf(M, mp[cc * BHQ + row]);
  float den = 0.f;
  float4 o = make_float4(0.f, 0.f, 0.f, 0.f);
  for (int cc = 0; cc < cb; ++cc) {
    const float w = exp2f(mp[cc * BHQ + row] - M);
    den += lp[cc * BHQ + row] * w;
    const float4 v = ((const float4*)op)[(size_t)cc * (BHQ * (DH / 4)) + idx];
    o.x += w * v.x; o.y += w * v.y; o.z += w * v.z; o.w += w * v.w;
  }
  const float inv = 1.0f / den;
  ((float4*)out)[idx] = make_float4(o.x * inv, o.y * inv, o.z * inv, o.w * inv);
}

extern "C" void kernel_launch(void* const* d_in, const int* in_sizes, int n_in,
                              void* d_out, int out_size, void* d_ws, size_t ws_size,
                              hipStream_t stream) {
  const float* q  = (const float*)d_in[0];
  const float* kc = (const float*)d_in[1];
  const float* vc = (const float*)d_in[2];
  const int* bt   = (const int*)d_in[3];
  const int* sl   = (const int*)d_in[4];
  float* out = (float*)d_out;

  const size_t perchunk = (size_t)BHQ * DH * sizeof(float) + (size_t)BHQ * 2 * sizeof(float);
  int nc = 1;
  if (ws_size >= 6 * perchunk) nc = 6;         // balanced ~12-tile chunks
  else if (ws_size >= 4 * perchunk) nc = 4;
  else if (ws_size >= 2 * perchunk) nc = 2;

  float* op = (nc == 1) ? out : (float*)d_ws;
  float* mp = (float*)d_ws + (size_t)nc * BHQ * DH;
  float* lp = mp + (size_t)nc * BHQ;

  paged_attn_kernel<<<dim3(BB * HH * nc), dim3(512), 0, stream>>>(q, kc, vc, bt, sl, op, mp, lp, nc);
  if (nc > 1)
    combine_kernel<<<dim3(BHQ * DH / 4 / 256), dim3(256), 0, stream>>>(op, mp, lp, sl, out, nc);
}

// Round 8
// 135.271 us; speedup vs baseline: 1.3746x; 1.1957x over previous
//
#include <hip/hip_runtime.h>
#include <hip/hip_bf16.h>

// Problem constants
#define BB     8
#define HH     16
#define QLEN   256
#define DH     128
#define BSZ    16
#define MAXB   256
#define KT     64            // kv tile
#define BHQ    (BB*HH*QLEN)  // 32768 rows
#define VROW   144           // V^T row stride in bytes (64 kv * 2B + 16 pad)

typedef __attribute__((ext_vector_type(8)))  short bf16x8;
typedef __attribute__((ext_vector_type(16))) float f32x16;

__device__ __forceinline__ unsigned pk2(float a, float b) {   // a -> low bf16, b -> high
  union { __hip_bfloat162 h; unsigned u; } c;
  c.h = __float22bfloat162_rn(make_float2(a, b));
  return c.u;
}

__device__ __forceinline__ float fexp2(float x) {
#if __has_builtin(__builtin_amdgcn_exp2f)
  return __builtin_amdgcn_exp2f(x);
#else
  return exp2f(x);
#endif
}

__device__ __forceinline__ f32x16 mfma32(bf16x8 a, bf16x8 b, f32x16 c) {
  return __builtin_amdgcn_mfma_f32_32x32x16_bf16(a, b, c, 0, 0, 0);
}

// Block = (bh, c): 512 thr / 8 waves; wave owns ONE 32x32 q-tile (q = qbase + lane&31).
// All 256 q rows in one block -> each staged KV byte feeds full Q via LDS.
// 32x32x16 MFMA throughout (2x FLOP/cycle vs 16x16x16 PV, 4x fewer instructions):
//   S^T = mfma32(A=K[kv32][d16], B=Q^T[d16][q32]) : lane holds q=lane&31,
//         kv rows (reg&3)+8*(reg>>2)+4*(lane>>5) per 32-kv tile.
//   softmax: lane-local over 32 scores + ONE shfl_xor(32) (partner holds other rows).
//   P^T B-frags built in-register: cross-half exchange via shfl_xor(lane^32)+cndmask.
//   O^T = mfma32(A=V^T[d32][kv16], B=P^T[kv16][q32]) : 4 dt x 4 kvb.
// LDS double-buffered; ONE barrier per tile; tile t+1 loads issued AFTER barrier.
// Defer-max (T13): skip acc rescale while __all(mx - m <= 8)  (P bounded 2^8).
// K LDS: [64][128] bf16 row-major, XOR swizzle ((row&7)<<4) on 16B units.
// V LDS: [128 d][64 kv] bf16 (V^T), row stride 144 B, kv-byte-offset XOR
//        (((d>>3)&7)<<4) (16B-granular) -> b128 reads contiguous, writes ~free.
__launch_bounds__(512, 2)
__global__ void paged_attn_kernel(const float* __restrict__ qg,
                                  const float* __restrict__ kc,
                                  const float* __restrict__ vc,
                                  const int* __restrict__ bt,
                                  const int* __restrict__ sl,
                                  float* __restrict__ opart,   // [nkv][BHQ][DH] (or out if nkv==1)
                                  float* __restrict__ mpart,   // [nkv][BHQ]
                                  float* __restrict__ lpart,   // [nkv][BHQ]
                                  int nkv) {
  __shared__ __align__(16) char kls[2][KT * DH * 2];   // 2 x 16 KiB
  __shared__ __align__(16) char vls[2][DH * VROW];     // 2 x 18 KiB
  __shared__ int btab[MAXB];                           // 1 KiB

  const int tid  = threadIdx.x;
  const int wave = tid >> 6;    // 0..7
  const int lane = tid & 63;
  const int ll   = lane & 31;   // q-column within wave tile
  const int hi   = lane >> 5;   // k-half for MFMA operands

  const int bid = blockIdx.x;
  const int c   = bid % nkv;
  const int bh  = bid / nkv;
  const int b   = bh >> 4;      // H = 16
  const int h   = bh & 15;

  const int seq = sl[b];
  const int nt  = (seq + KT - 1) / KT;
  const int per = (nt + nkv - 1) / nkv;
  const int t0  = c * per;
  const int t1  = (t0 + per < nt) ? (t0 + per) : nt;

  if (tid < MAXB) btab[tid] = bt[b * MAXB + tid];
  __syncthreads();  // btab visible

  // ---- prefetch registers for one tile ----
  float4 kreg[2][2];   // K slot i: row (i*512+tid)>>4, 16B chunk (i*512+tid)&15 (2 float4)
  float4 vreg[2][2];   // V slot i: d4 = slot&31 (coalesced), kvp = slot>>5; rows 2kvp,2kvp+1

#define ISSUE_LOADS(KV0)                                                        \
  {                                                                             \
    _Pragma("unroll")                                                           \
    for (int i = 0; i < 2; ++i) {                                               \
      const int slot = i * 512 + tid;                                           \
      const int row = slot >> 4, c16 = slot & 15;                               \
      const int kv = (KV0) + row;                                               \
      const int phys = btab[kv >> 4];                                           \
      const size_t gb = (((size_t)phys * HH + h) * BSZ + (kv & 15)) * DH + c16 * 8; \
      kreg[i][0] = *(const float4*)(kc + gb);                                   \
      kreg[i][1] = *(const float4*)(kc + gb + 4);                               \
    }                                                                           \
    _Pragma("unroll")                                                           \
    for (int i = 0; i < 2; ++i) {                                               \
      const int slot = i * 512 + tid;                                           \
      const int d4 = slot & 31, kvp = slot >> 5;                                \
      const int kv = (KV0) + kvp * 2;                                           \
      const int phys = btab[kv >> 4];                                           \
      const size_t gb = (((size_t)phys * HH + h) * BSZ + (kv & 15)) * DH + d4 * 4; \
      vreg[i][0] = *(const float4*)(vc + gb);                                   \
      vreg[i][1] = *(const float4*)(vc + gb + DH);                              \
    }                                                                           \
  }

  ISSUE_LOADS(t0 * KT)   // prologue: tile t0 in flight

  // ---- Q fragments (B-operand): lane = col q, provides Q[q][d = ks*16 + hi*8 + j] ----
  const float qscale = 0.08838834764831845f * 1.4426950408889634f;  // 1/sqrt(128)*log2(e)
  const int qbase = wave * 32;
  bf16x8 qf[8];
  {
    const float* qr = qg + ((size_t)bh * QLEN + qbase + ll) * DH;
#pragma unroll
    for (int ks = 0; ks < 8; ++ks) {
      const int d0 = ks * 16 + hi * 8;
      const float4 a  = *(const float4*)(qr + d0);
      const float4 bv = *(const float4*)(qr + d0 + 4);
      union { bf16x8 v; unsigned u[4]; } w;
      w.u[0] = pk2(a.x * qscale,  a.y * qscale);
      w.u[1] = pk2(a.z * qscale,  a.w * qscale);
      w.u[2] = pk2(bv.x * qscale, bv.y * qscale);
      w.u[3] = pk2(bv.z * qscale, bv.w * qscale);
      qf[ks] = w.v;
    }
  }

  f32x16 accT[4];   // O^T: lane q=qbase+ll, d = dt*32 + (reg&3) + 8*(reg>>2) + 4*hi
#pragma unroll
  for (int dt = 0; dt < 4; ++dt)
#pragma unroll
    for (int i = 0; i < 16; ++i) accT[dt][i] = 0.f;
  float mrow = -1e30f, lrow = 0.f;

  for (int t = t0; t < t1; ++t) {
    const int kv0 = t * KT;
    const int bb  = t & 1;

    // ---- convert prefetched fp32 -> bf16, write LDS buf bb (vmcnt waits here) ----
#pragma unroll
    for (int i = 0; i < 2; ++i) {
      const int slot = i * 512 + tid;
      const int row = slot >> 4, c16 = slot & 15;
      union { uint4 u4; unsigned u[4]; } w;
      w.u[0] = pk2(kreg[i][0].x, kreg[i][0].y);
      w.u[1] = pk2(kreg[i][0].z, kreg[i][0].w);
      w.u[2] = pk2(kreg[i][1].x, kreg[i][1].y);
      w.u[3] = pk2(kreg[i][1].z, kreg[i][1].w);
      const int kb = (row * 256 + c16 * 16) ^ ((row & 7) << 4);
      *(uint4*)(kls[bb] + kb) = w.u4;
    }
#pragma unroll
    for (int i = 0; i < 2; ++i) {
      const int slot = i * 512 + tid;
      const int d4 = slot & 31, kvp = slot >> 5;
      const float* aa = (const float*)&vreg[i][0];
      const float* bp = (const float*)&vreg[i][1];
#pragma unroll
      for (int jj = 0; jj < 4; ++jj) {
        const int d = d4 * 4 + jj;
        const int vb = d * VROW + ((kvp * 4) ^ (((d >> 3) & 7) << 4));
        *(unsigned*)(vls[bb] + vb) = pk2(aa[jj], bp[jj]);   // low = even kv
      }
    }

    __syncthreads();  // buf bb ready; all waves done computing tile t-1

    // ---- issue tile t+1 loads AFTER barrier (not drained by it) ----
    if (t + 1 < t1) ISSUE_LOADS((t + 1) * KT)

    // ---- S^T = K · Q^T : 2 kv-tiles of 32, K-dim = d (8 x 16) ----
    f32x16 s[2];
#pragma unroll
    for (int kvt = 0; kvt < 2; ++kvt) {
#pragma unroll
      for (int i = 0; i < 16; ++i) s[kvt][i] = 0.f;
      const int krow  = kvt * 32 + ll;
      const int kbase = krow * 256;
      const int ksw   = (krow & 7) << 4;
#pragma unroll
      for (int ks = 0; ks < 8; ++ks) {
        const bf16x8 kf = *(const bf16x8*)(kls[bb] + kbase + (((ks * 32 + hi * 16)) ^ ksw));
        s[kvt] = mfma32(kf, qf[ks], s[kvt]);
      }
    }

    // ---- online softmax: lane owns q-row; 32 scores, partner (lane^32) has other 32 ----
    if (kv0 + KT > seq) {
#pragma unroll
      for (int kvt = 0; kvt < 2; ++kvt)
#pragma unroll
        for (int r = 0; r < 16; ++r) {
          const int kvg = kv0 + kvt * 32 + (r & 3) + 8 * (r >> 2) + 4 * hi;
          if (kvg >= seq) s[kvt][r] = -1e30f;
        }
    }
    float mx = s[0][0];
#pragma unroll
    for (int kvt = 0; kvt < 2; ++kvt)
#pragma unroll
      for (int r = 0; r < 16; ++r) mx = fmaxf(mx, s[kvt][r]);
    mx = fmaxf(mx, __shfl_xor(mx, 32));
    // T13 defer-max: rescale only when some lane's max grew past m+8.
    if (!__all(mx - mrow <= 8.0f)) {
      const float mnew  = fmaxf(mrow, mx);
      const float alpha = fexp2(mrow - mnew);
      mrow = mnew;
      lrow *= alpha;
#pragma unroll
      for (int dt = 0; dt < 4; ++dt)
#pragma unroll
        for (int i = 0; i < 16; ++i) accT[dt][i] *= alpha;
    }
    float rs = 0.f;
#pragma unroll
    for (int kvt = 0; kvt < 2; ++kvt)
#pragma unroll
      for (int r = 0; r < 16; ++r) {
        s[kvt][r] = fexp2(s[kvt][r] - mrow);   // bounded by 2^8
        rs += s[kvt][r];
      }
    rs += __shfl_xor(rs, 32);
    lrow += rs;

    // ---- pack P (consecutive kv pairs: regs 2p,2p+1 -> kv k,k+1) ----
    unsigned pkk[2][8];
#pragma unroll
    for (int kvt = 0; kvt < 2; ++kvt)
#pragma unroll
      for (int p = 0; p < 8; ++p)
        pkk[kvt][p] = pk2(s[kvt][2 * p], s[kvt][2 * p + 1]);

    // ---- build P^T B-frags: cross-half exchange (lane <-> lane^32) ----
    // target u32[jj] = pk[from half jj>>1][p = 4*(kvb&1) + 2*hi + (jj&1)]
    bf16x8 pb[4];
#pragma unroll
    for (int kvb = 0; kvb < 4; ++kvb) {
      const int kvt = kvb >> 1;
      const int base = (kvb & 1) * 4;
      const unsigned send0 = hi ? pkk[kvt][base]     : pkk[kvt][base + 2];
      const unsigned send1 = hi ? pkk[kvt][base + 1] : pkk[kvt][base + 3];
      const unsigned recv0 = (unsigned)__shfl_xor((int)send0, 32);
      const unsigned recv1 = (unsigned)__shfl_xor((int)send1, 32);
      union { bf16x8 v; unsigned u[4]; } w;
      w.u[0] = hi ? recv0 : pkk[kvt][base];       // P from lower half, p
      w.u[1] = hi ? recv1 : pkk[kvt][base + 1];   // P from lower half, p+1
      w.u[2] = hi ? pkk[kvt][base + 2] : recv0;   // P from upper half, p
      w.u[3] = hi ? pkk[kvt][base + 3] : recv1;   // P from upper half, p+1
      pb[kvb] = w.v;
    }

    // ---- O^T += V^T · P^T : 4 d-tiles x 4 kv-blocks of 16 ----
#pragma unroll
    for (int dt = 0; dt < 4; ++dt) {
      const int d  = dt * 32 + ll;
      const int sw = ((d >> 3) & 7) << 4;
      const char* vbp = vls[bb] + d * VROW;
#pragma unroll
      for (int kvb = 0; kvb < 4; ++kvb) {
        const bf16x8 va = *(const bf16x8*)(vbp + ((kvb * 32 + hi * 16) ^ sw));
        accT[dt] = mfma32(va, pb[kvb], accT[dt]);
      }
    }
  }

  // ---- epilogue: lane writes q-row qbase+ll; d = dt*32 + 8*r + 4*hi + 0..3 ----
  const int grow = bh * QLEN + qbase + ll;
  if (nkv == 1) {
    const float inv = 1.0f / lrow;
    float* orow = opart + (size_t)grow * DH;
#pragma unroll
    for (int dt = 0; dt < 4; ++dt)
#pragma unroll
      for (int r = 0; r < 4; ++r) {
        float4 v = make_float4(accT[dt][4 * r] * inv,     accT[dt][4 * r + 1] * inv,
                               accT[dt][4 * r + 2] * inv, accT[dt][4 * r + 3] * inv);
        *(float4*)(orow + dt * 32 + 8 * r + 4 * hi) = v;
      }
  } else {
    float* orow = opart + ((size_t)c * BHQ + grow) * DH;
#pragma unroll
    for (int dt = 0; dt < 4; ++dt)
#pragma unroll
      for (int r = 0; r < 4; ++r) {
        float4 v = make_float4(accT[dt][4 * r],     accT[dt][4 * r + 1],
                               accT[dt][4 * r + 2], accT[dt][4 * r + 3]);
        *(float4*)(orow + dt * 32 + 8 * r + 4 * hi) = v;   // unnormalized
      }
    if (hi == 0) {
      mpart[c * BHQ + grow] = mrow;
      lpart[c * BHQ + grow] = lrow;
    }
  }
}

__global__ void combine_kernel(const float* __restrict__ op,
                               const float* __restrict__ mp,
                               const float* __restrict__ lp,
                               float* __restrict__ out, int nkv) {
  const int idx = blockIdx.x * 256 + threadIdx.x;  // float4 index over BHQ*DH/4
  const int row = idx >> 5;                        // 32 float4 per row
  float M = -1e30f;
  for (int cc = 0; cc < nkv; ++cc) M = fmaxf(M, mp[cc * BHQ + row]);
  float den = 0.f;
  float4 o = make_float4(0.f, 0.f, 0.f, 0.f);
  for (int cc = 0; cc < nkv; ++cc) {
    const float w = exp2f(mp[cc * BHQ + row] - M);
    den += lp[cc * BHQ + row] * w;
    const float4 v = ((const float4*)op)[(size_t)cc * (BHQ * (DH / 4)) + idx];
    o.x += w * v.x; o.y += w * v.y; o.z += w * v.z; o.w += w * v.w;
  }
  const float inv = 1.0f / den;
  ((float4*)out)[idx] = make_float4(o.x * inv, o.y * inv, o.z * inv, o.w * inv);
}

extern "C" void kernel_launch(void* const* d_in, const int* in_sizes, int n_in,
                              void* d_out, int out_size, void* d_ws, size_t ws_size,
                              hipStream_t stream) {
  const float* q  = (const float*)d_in[0];
  const float* kc = (const float*)d_in[1];
  const float* vc = (const float*)d_in[2];
  const int* bt   = (const int*)d_in[3];
  const int* sl   = (const int*)d_in[4];
  float* out = (float*)d_out;

  const size_t perchunk = (size_t)BHQ * DH * sizeof(float) + (size_t)BHQ * 2 * sizeof(float);
  int nkv = 1;
  if (ws_size >= 4 * perchunk) nkv = 4;        // 512 blocks: best measured (r5)
  else if (ws_size >= 2 * perchunk) nkv = 2;

  float* op = (nkv == 1) ? out : (float*)d_ws;
  float* mp = (float*)d_ws + (size_t)nkv * BHQ * DH;
  float* lp = mp + (size_t)nkv * BHQ;

  paged_attn_kernel<<<dim3(BB * HH * nkv), dim3(512), 0, stream>>>(q, kc, vc, bt, sl, op, mp, lp, nkv);
  if (nkv > 1)
    combine_kernel<<<dim3(BHQ * DH / 4 / 256), dim3(256), 0, stream>>>(op, mp, lp, out, nkv);
}

// Round 9
// 128.288 us; speedup vs baseline: 1.4495x; 1.0544x over previous
//
#include <hip/hip_runtime.h>
#include <hip/hip_bf16.h>

// Problem constants
#define BB     8
#define HH     16
#define QLEN   256
#define DH     128
#define BSZ    16
#define MAXB   256
#define KT     64            // kv tile
#define BHQ    (BB*HH*QLEN)  // 32768 rows
#define VROW   144           // V^T row stride in bytes (64 kv * 2B + 16 pad)

typedef __attribute__((ext_vector_type(8)))  short bf16x8;
typedef __attribute__((ext_vector_type(16))) float f32x16;

__device__ __forceinline__ unsigned pk2(float a, float b) {   // a -> low bf16, b -> high
  union { __hip_bfloat162 h; unsigned u; } c;
  c.h = __float22bfloat162_rn(make_float2(a, b));
  return c.u;
}

__device__ __forceinline__ float bf2f(unsigned short u) {
  union { float f; unsigned u; } c; c.u = ((unsigned)u) << 16; return c.f;
}

__device__ __forceinline__ float fexp2(float x) {
#if __has_builtin(__builtin_amdgcn_exp2f)
  return __builtin_amdgcn_exp2f(x);
#else
  return exp2f(x);
#endif
}

__device__ __forceinline__ f32x16 mfma32(bf16x8 a, bf16x8 b, f32x16 c) {
  return __builtin_amdgcn_mfma_f32_32x32x16_bf16(a, b, c, 0, 0, 0);
}

// Block = (bh, c): 512 thr / 8 waves; wave owns ONE 32x32 q-tile (q = qbase + lane&31).
// All 256 q rows in one block -> each staged KV byte feeds full Q via LDS.
// 32x32x16 MFMA throughout. Swapped-QK^T:
//   S^T = mfma32(A=K[kv32][d16], B=Q^T[d16][q32]) : lane holds q=lane&31,
//         kv rows (reg&3)+8*(reg>>2)+4*(lane>>5) per 32-kv tile.
//   softmax: lane-local, TREE max/sum (dep depth 5 vs 32) + ONE shfl_xor(32).
//   P^T B-frags built in-register: cross-half exchange via shfl_xor(lane^32)+cndmask.
//   O^T = mfma32(A=V^T[d32][kv16], B=P^T[kv16][q32]) : 4 dt x 4 kvb.
// LDS double-buffered; ONE barrier per tile; tile t+1 loads issued AFTER the
// barrier (m97: the barrier's vmcnt(0) drain would flush pre-issued loads).
// Defer-max (T13): skip acc rescale while __all(mx - m <= 8)  (P bounded 2^8).
// Partial O written as bf16 (halves combine round-trip traffic).
// K LDS: [64][128] bf16 row-major, XOR swizzle ((row&7)<<4) on 16B units.
// V LDS: [128 d][64 kv] bf16 (V^T), row stride 144 B, kv-byte-offset XOR
//        (((d>>3)&7)<<4) (16B-granular) -> b128 reads contiguous.
__launch_bounds__(512, 2)
__global__ void paged_attn_kernel(const float* __restrict__ qg,
                                  const float* __restrict__ kc,
                                  const float* __restrict__ vc,
                                  const int* __restrict__ bt,
                                  const int* __restrict__ sl,
                                  float* __restrict__ outd,              // direct out (nkv==1)
                                  __hip_bfloat16* __restrict__ opart,    // [nkv][BHQ][DH] bf16
                                  float* __restrict__ mpart,             // [nkv][BHQ]
                                  float* __restrict__ lpart,             // [nkv][BHQ]
                                  int nkv) {
  __shared__ __align__(16) char kls[2][KT * DH * 2];   // 2 x 16 KiB
  __shared__ __align__(16) char vls[2][DH * VROW];     // 2 x 18 KiB
  __shared__ int btab[MAXB];                           // 1 KiB

  const int tid  = threadIdx.x;
  const int wave = tid >> 6;    // 0..7
  const int lane = tid & 63;
  const int ll   = lane & 31;   // q-column within wave tile
  const int hi   = lane >> 5;   // k-half for MFMA operands

  const int bid = blockIdx.x;
  const int c   = bid % nkv;
  const int bh  = bid / nkv;
  const int b   = bh >> 4;      // H = 16
  const int h   = bh & 15;

  const int seq = sl[b];
  const int nt  = (seq + KT - 1) / KT;
  const int per = (nt + nkv - 1) / nkv;
  const int t0  = c * per;
  const int t1  = (t0 + per < nt) ? (t0 + per) : nt;

  if (tid < MAXB) btab[tid] = bt[b * MAXB + tid];
  __syncthreads();  // btab visible

  // ---- prefetch registers for one tile ----
  float4 kreg[2][2];   // K slot i: row (i*512+tid)>>4, 16B chunk (i*512+tid)&15 (2 float4)
  float4 vreg[2][2];   // V slot i: d4 = slot&31 (coalesced), kvp = slot>>5; rows 2kvp,2kvp+1

#define ISSUE_LOADS(KV0)                                                        \
  {                                                                             \
    _Pragma("unroll")                                                           \
    for (int i = 0; i < 2; ++i) {                                               \
      const int slot = i * 512 + tid;                                           \
      const int row = slot >> 4, c16 = slot & 15;                               \
      const int kv = (KV0) + row;                                               \
      const int phys = btab[kv >> 4];                                           \
      const size_t gb = (((size_t)phys * HH + h) * BSZ + (kv & 15)) * DH + c16 * 8; \
      kreg[i][0] = *(const float4*)(kc + gb);                                   \
      kreg[i][1] = *(const float4*)(kc + gb + 4);                               \
    }                                                                           \
    _Pragma("unroll")                                                           \
    for (int i = 0; i < 2; ++i) {                                               \
      const int slot = i * 512 + tid;                                           \
      const int d4 = slot & 31, kvp = slot >> 5;                                \
      const int kv = (KV0) + kvp * 2;                                           \
      const int phys = btab[kv >> 4];                                           \
      const size_t gb = (((size_t)phys * HH + h) * BSZ + (kv & 15)) * DH + d4 * 4; \
      vreg[i][0] = *(const float4*)(vc + gb);                                   \
      vreg[i][1] = *(const float4*)(vc + gb + DH);                              \
    }                                                                           \
  }

  ISSUE_LOADS(t0 * KT)   // prologue: tile t0 in flight

  // ---- Q fragments (B-operand): lane = col q, provides Q[q][d = ks*16 + hi*8 + j] ----
  const float qscale = 0.08838834764831845f * 1.4426950408889634f;  // 1/sqrt(128)*log2(e)
  const int qbase = wave * 32;
  bf16x8 qf[8];
  {
    const float* qr = qg + ((size_t)bh * QLEN + qbase + ll) * DH;
#pragma unroll
    for (int ks = 0; ks < 8; ++ks) {
      const int d0 = ks * 16 + hi * 8;
      const float4 a  = *(const float4*)(qr + d0);
      const float4 bv = *(const float4*)(qr + d0 + 4);
      union { bf16x8 v; unsigned u[4]; } w;
      w.u[0] = pk2(a.x * qscale,  a.y * qscale);
      w.u[1] = pk2(a.z * qscale,  a.w * qscale);
      w.u[2] = pk2(bv.x * qscale, bv.y * qscale);
      w.u[3] = pk2(bv.z * qscale, bv.w * qscale);
      qf[ks] = w.v;
    }
  }

  f32x16 accT[4];   // O^T: lane q=qbase+ll, d = dt*32 + (reg&3) + 8*(reg>>2) + 4*hi
#pragma unroll
  for (int dt = 0; dt < 4; ++dt)
#pragma unroll
    for (int i = 0; i < 16; ++i) accT[dt][i] = 0.f;
  float mrow = -1e30f, lrow = 0.f;

  for (int t = t0; t < t1; ++t) {
    const int kv0 = t * KT;
    const int bb  = t & 1;

    // ---- convert prefetched fp32 -> bf16, write LDS buf bb (vmcnt waits here) ----
#pragma unroll
    for (int i = 0; i < 2; ++i) {
      const int slot = i * 512 + tid;
      const int row = slot >> 4, c16 = slot & 15;
      union { uint4 u4; unsigned u[4]; } w;
      w.u[0] = pk2(kreg[i][0].x, kreg[i][0].y);
      w.u[1] = pk2(kreg[i][0].z, kreg[i][0].w);
      w.u[2] = pk2(kreg[i][1].x, kreg[i][1].y);
      w.u[3] = pk2(kreg[i][1].z, kreg[i][1].w);
      const int kb = (row * 256 + c16 * 16) ^ ((row & 7) << 4);
      *(uint4*)(kls[bb] + kb) = w.u4;
    }
#pragma unroll
    for (int i = 0; i < 2; ++i) {
      const int slot = i * 512 + tid;
      const int d4 = slot & 31, kvp = slot >> 5;
      const float* aa = (const float*)&vreg[i][0];
      const float* bp = (const float*)&vreg[i][1];
#pragma unroll
      for (int jj = 0; jj < 4; ++jj) {
        const int d = d4 * 4 + jj;
        const int vb = d * VROW + ((kvp * 4) ^ (((d >> 3) & 7) << 4));
        *(unsigned*)(vls[bb] + vb) = pk2(aa[jj], bp[jj]);   // low = even kv
      }
    }

    __syncthreads();  // buf bb ready; all waves done computing tile t-1

    // ---- issue tile t+1 loads AFTER barrier (not drained by it) ----
    if (t + 1 < t1) ISSUE_LOADS((t + 1) * KT)

    // ---- S^T = K · Q^T : 2 kv-tiles of 32, K-dim = d (8 x 16) ----
    f32x16 s[2];
#pragma unroll
    for (int kvt = 0; kvt < 2; ++kvt) {
#pragma unroll
      for (int i = 0; i < 16; ++i) s[kvt][i] = 0.f;
      const int krow  = kvt * 32 + ll;
      const int kbase = krow * 256;
      const int ksw   = (krow & 7) << 4;
#pragma unroll
      for (int ks = 0; ks < 8; ++ks) {
        const bf16x8 kf = *(const bf16x8*)(kls[bb] + kbase + (((ks * 32 + hi * 16)) ^ ksw));
        s[kvt] = mfma32(kf, qf[ks], s[kvt]);
      }
    }

    // ---- online softmax: lane owns q-row; 32 scores, partner (lane^32) has other 32 ----
    if (kv0 + KT > seq) {
#pragma unroll
      for (int kvt = 0; kvt < 2; ++kvt)
#pragma unroll
        for (int r = 0; r < 16; ++r) {
          const int kvg = kv0 + kvt * 32 + (r & 3) + 8 * (r >> 2) + 4 * hi;
          if (kvg >= seq) s[kvt][r] = -1e30f;
        }
    }
    // tree max (dep depth ~5 instead of 32)
    float tm[16];
#pragma unroll
    for (int r = 0; r < 16; ++r) tm[r] = fmaxf(s[0][r], s[1][r]);
#pragma unroll
    for (int w2 = 8; w2 >= 1; w2 >>= 1)
#pragma unroll
      for (int r = 0; r < w2; ++r) tm[r] = fmaxf(tm[r], tm[r + w2]);
    float mx = fmaxf(tm[0], __shfl_xor(tm[0], 32));
    // T13 defer-max: rescale only when some lane's max grew past m+8.
    if (!__all(mx - mrow <= 8.0f)) {
      const float mnew  = fmaxf(mrow, mx);
      const float alpha = fexp2(mrow - mnew);
      mrow = mnew;
      lrow *= alpha;
#pragma unroll
      for (int dt = 0; dt < 4; ++dt)
#pragma unroll
        for (int i = 0; i < 16; ++i) accT[dt][i] *= alpha;
    }
#pragma unroll
    for (int kvt = 0; kvt < 2; ++kvt)
#pragma unroll
      for (int r = 0; r < 16; ++r)
        s[kvt][r] = fexp2(s[kvt][r] - mrow);   // bounded by 2^8
    // tree sum
    float ts[16];
#pragma unroll
    for (int r = 0; r < 16; ++r) ts[r] = s[0][r] + s[1][r];
#pragma unroll
    for (int w2 = 8; w2 >= 1; w2 >>= 1)
#pragma unroll
      for (int r = 0; r < w2; ++r) ts[r] += ts[r + w2];
    lrow += ts[0] + __shfl_xor(ts[0], 32);

    // ---- pack P (consecutive kv pairs: regs 2p,2p+1 -> kv k,k+1) ----
    unsigned pkk[2][8];
#pragma unroll
    for (int kvt = 0; kvt < 2; ++kvt)
#pragma unroll
      for (int p = 0; p < 8; ++p)
        pkk[kvt][p] = pk2(s[kvt][2 * p], s[kvt][2 * p + 1]);

    // ---- build P^T B-frags: cross-half exchange (lane <-> lane^32) ----
    bf16x8 pb[4];
#pragma unroll
    for (int kvb = 0; kvb < 4; ++kvb) {
      const int kvt = kvb >> 1;
      const int base = (kvb & 1) * 4;
      const unsigned send0 = hi ? pkk[kvt][base]     : pkk[kvt][base + 2];
      const unsigned send1 = hi ? pkk[kvt][base + 1] : pkk[kvt][base + 3];
      const unsigned recv0 = (unsigned)__shfl_xor((int)send0, 32);
      const unsigned recv1 = (unsigned)__shfl_xor((int)send1, 32);
      union { bf16x8 v; unsigned u[4]; } w;
      w.u[0] = hi ? recv0 : pkk[kvt][base];
      w.u[1] = hi ? recv1 : pkk[kvt][base + 1];
      w.u[2] = hi ? pkk[kvt][base + 2] : recv0;
      w.u[3] = hi ? pkk[kvt][base + 3] : recv1;
      pb[kvb] = w.v;
    }

    // ---- O^T += V^T · P^T : 4 d-tiles x 4 kv-blocks of 16 ----
#pragma unroll
    for (int dt = 0; dt < 4; ++dt) {
      const int d  = dt * 32 + ll;
      const int sw = ((d >> 3) & 7) << 4;
      const char* vbp = vls[bb] + d * VROW;
#pragma unroll
      for (int kvb = 0; kvb < 4; ++kvb) {
        const bf16x8 va = *(const bf16x8*)(vbp + ((kvb * 32 + hi * 16) ^ sw));
        accT[dt] = mfma32(va, pb[kvb], accT[dt]);
      }
    }
  }

  // ---- epilogue: lane writes q-row qbase+ll; d = dt*32 + 8*r + 4*hi + 0..3 ----
  const int grow = bh * QLEN + qbase + ll;
  if (nkv == 1) {
    const float inv = 1.0f / lrow;
    float* orow = outd + (size_t)grow * DH;
#pragma unroll
    for (int dt = 0; dt < 4; ++dt)
#pragma unroll
      for (int r = 0; r < 4; ++r) {
        float4 v = make_float4(accT[dt][4 * r] * inv,     accT[dt][4 * r + 1] * inv,
                               accT[dt][4 * r + 2] * inv, accT[dt][4 * r + 3] * inv);
        *(float4*)(orow + dt * 32 + 8 * r + 4 * hi) = v;
      }
  } else {
    __hip_bfloat16* orow = opart + ((size_t)c * BHQ + grow) * DH;
#pragma unroll
    for (int dt = 0; dt < 4; ++dt)
#pragma unroll
      for (int r = 0; r < 4; ++r) {
        const unsigned lo2 = pk2(accT[dt][4 * r],     accT[dt][4 * r + 1]);
        const unsigned hi2 = pk2(accT[dt][4 * r + 2], accT[dt][4 * r + 3]);
        *(uint2*)((char*)orow + (dt * 32 + 8 * r + 4 * hi) * 2) = make_uint2(lo2, hi2);
      }
    if (hi == 0) {
      mpart[c * BHQ + grow] = mrow;
      lpart[c * BHQ + grow] = lrow;
    }
  }
}

__global__ void combine_kernel(const __hip_bfloat16* __restrict__ op,
                               const float* __restrict__ mp,
                               const float* __restrict__ lp,
                               float* __restrict__ out, int nkv) {
  const int idx = blockIdx.x * 256 + threadIdx.x;  // 8-elem group over BHQ*DH/8
  const int row = idx >> 4;                        // 16 groups per row (128/8)
  float M = -1e30f;
  for (int cc = 0; cc < nkv; ++cc) M = fmaxf(M, mp[cc * BHQ + row]);
  float den = 0.f;
  float o[8] = {0.f, 0.f, 0.f, 0.f, 0.f, 0.f, 0.f, 0.f};
  for (int cc = 0; cc < nkv; ++cc) {
    const float w = exp2f(mp[cc * BHQ + row] - M);
    den += lp[cc * BHQ + row] * w;
    const uint4 v = *(const uint4*)((const char*)op + ((size_t)cc * BHQ * DH + (size_t)idx * 8) * 2);
    const unsigned u[4] = {v.x, v.y, v.z, v.w};
#pragma unroll
    for (int j = 0; j < 4; ++j) {
      o[2 * j]     += w * bf2f((unsigned short)(u[j] & 0xffffu));
      o[2 * j + 1] += w * bf2f((unsigned short)(u[j] >> 16));
    }
  }
  const float inv = 1.0f / den;
  float4* dst = (float4*)(out + (size_t)idx * 8);
  dst[0] = make_float4(o[0] * inv, o[1] * inv, o[2] * inv, o[3] * inv);
  dst[1] = make_float4(o[4] * inv, o[5] * inv, o[6] * inv, o[7] * inv);
}

extern "C" void kernel_launch(void* const* d_in, const int* in_sizes, int n_in,
                              void* d_out, int out_size, void* d_ws, size_t ws_size,
                              hipStream_t stream) {
  const float* q  = (const float*)d_in[0];
  const float* kc = (const float*)d_in[1];
  const float* vc = (const float*)d_in[2];
  const int* bt   = (const int*)d_in[3];
  const int* sl   = (const int*)d_in[4];
  float* out = (float*)d_out;

  // per-chunk: bf16 O partial + fp32 m + fp32 l
  const size_t perchunk = (size_t)BHQ * DH * sizeof(__hip_bfloat16) + (size_t)BHQ * 2 * sizeof(float);
  int nkv = 1;
  if (ws_size >= 4 * perchunk) nkv = 4;        // 512 blocks: best measured (r5)
  else if (ws_size >= 2 * perchunk) nkv = 2;

  __hip_bfloat16* op = (__hip_bfloat16*)d_ws;
  float* mp = (float*)((char*)d_ws + (size_t)nkv * BHQ * DH * sizeof(__hip_bfloat16));
  float* lp = mp + (size_t)nkv * BHQ;

  paged_attn_kernel<<<dim3(BB * HH * nkv), dim3(512), 0, stream>>>(q, kc, vc, bt, sl, out, op, mp, lp, nkv);
  if (nkv > 1)
    combine_kernel<<<dim3(BHQ * DH / 8 / 256), dim3(256), 0, stream>>>(op, mp, lp, out, nkv);
}

// Round 10
// 123.484 us; speedup vs baseline: 1.5059x; 1.0389x over previous
//
#include <hip/hip_runtime.h>
#include <hip/hip_bf16.h>

// Problem constants
#define BB     8
#define HH     16
#define QLEN   256
#define DH     128
#define BSZ    16
#define MAXB   256
#define KT     64            // kv tile
#define BHQ    (BB*HH*QLEN)  // 32768 rows
#define VROW   144           // V^T row stride in bytes (64 kv * 2B + 16 pad)

typedef __attribute__((ext_vector_type(8)))  short bf16x8;
typedef __attribute__((ext_vector_type(16))) float f32x16;

__device__ __forceinline__ unsigned pk2(float a, float b) {   // a -> low bf16, b -> high
  union { __hip_bfloat162 h; unsigned u; } c;
  c.h = __float22bfloat162_rn(make_float2(a, b));
  return c.u;
}

__device__ __forceinline__ float bf2f(unsigned short u) {
  union { float f; unsigned u; } c; c.u = ((unsigned)u) << 16; return c.f;
}

__device__ __forceinline__ float fexp2(float x) {
#if __has_builtin(__builtin_amdgcn_exp2f)
  return __builtin_amdgcn_exp2f(x);
#else
  return exp2f(x);
#endif
}

__device__ __forceinline__ f32x16 mfma32(bf16x8 a, bf16x8 b, f32x16 c) {
  return __builtin_amdgcn_mfma_f32_32x32x16_bf16(a, b, c, 0, 0, 0);
}

// Block = (bh, c): 512 thr / 8 waves; wave owns ONE 32x32 q-tile (q = qbase + lane&31).
// All 256 q rows in one block -> each staged KV byte feeds full Q via LDS.
// 32x32x16 MFMA. Swapped-QK^T; softmax lane-local (tree) + ONE shfl_xor(32);
// P^T B-frags in-register via shfl_xor(lane^32)+selects.
// K LDS: CHUNK-MAJOR [c16 = d/8][kv ^ (c16&7)] in 16B units (4 KiB stride/chunk... 1 KiB
//        per chunk-row of 64 slots). QK A-frag reads are contiguous-permuted 512B runs
//        (conflict-free, vs 8-way in the old row-major+3-bit-XOR layout); staging
//        writes spread 2-way (free). Same XOR involution applied on write AND read.
// V LDS: [128 d][64 kv] bf16 (V^T), row stride 144 B, kv-offset XOR (((d>>3)&7)<<4).
// Pipeline per tile (T14 write-late): QK(t) -> stage-write(t+1 -> buf^1) ->
// issue loads(t+2) -> softmax(t) -> PV(t) -> barrier. Writes land ~700cy before
// the barrier; convert VALU hides QK MFMA latency; ONE barrier per tile.
// Defer-max (T13): skip acc rescale while __all(mx - m <= 8)  (P bounded 2^8).
// Partial O written as bf16 (halves combine round-trip traffic).
__launch_bounds__(512, 2)
__global__ void paged_attn_kernel(const float* __restrict__ qg,
                                  const float* __restrict__ kc,
                                  const float* __restrict__ vc,
                                  const int* __restrict__ bt,
                                  const int* __restrict__ sl,
                                  float* __restrict__ outd,              // direct out (nkv==1)
                                  __hip_bfloat16* __restrict__ opart,    // [nkv][BHQ][DH] bf16
                                  float* __restrict__ mpart,             // [nkv][BHQ]
                                  float* __restrict__ lpart,             // [nkv][BHQ]
                                  int nkv) {
  __shared__ __align__(16) char kls[2][16 * 1024];     // 2 x 16 KiB, chunk-major
  __shared__ __align__(16) char vls[2][DH * VROW];     // 2 x 18 KiB
  __shared__ int btab[MAXB];                           // 1 KiB

  const int tid  = threadIdx.x;
  const int wave = tid >> 6;    // 0..7
  const int lane = tid & 63;
  const int ll   = lane & 31;   // q-column within wave tile
  const int hi   = lane >> 5;   // k-half for MFMA operands

  const int bid = blockIdx.x;
  const int c   = bid % nkv;
  const int bh  = bid / nkv;
  const int b   = bh >> 4;      // H = 16
  const int h   = bh & 15;

  const int seq = sl[b];
  const int nt  = (seq + KT - 1) / KT;
  const int per = (nt + nkv - 1) / nkv;
  const int t0  = c * per;
  const int t1  = (t0 + per < nt) ? (t0 + per) : nt;

  if (tid < MAXB) btab[tid] = bt[b * MAXB + tid];
  __syncthreads();  // btab visible

  // ---- prefetch registers for one tile ----
  float4 kreg[2][2];   // K slot i: row (i*512+tid)>>4, 16B chunk (i*512+tid)&15 (2 float4)
  float4 vreg[2][2];   // V slot i: d4 = slot&31 (coalesced), kvp = slot>>5; rows 2kvp,2kvp+1

#define ISSUE_LOADS(KV0)                                                        \
  {                                                                             \
    _Pragma("unroll")                                                           \
    for (int i = 0; i < 2; ++i) {                                               \
      const int slot = i * 512 + tid;                                           \
      const int row = slot >> 4, c16 = slot & 15;                               \
      const int kv = (KV0) + row;                                               \
      const int phys = btab[kv >> 4];                                           \
      const size_t gb = (((size_t)phys * HH + h) * BSZ + (kv & 15)) * DH + c16 * 8; \
      kreg[i][0] = *(const float4*)(kc + gb);                                   \
      kreg[i][1] = *(const float4*)(kc + gb + 4);                               \
    }                                                                           \
    _Pragma("unroll")                                                           \
    for (int i = 0; i < 2; ++i) {                                               \
      const int slot = i * 512 + tid;                                           \
      const int d4 = slot & 31, kvp = slot >> 5;                                \
      const int kv = (KV0) + kvp * 2;                                           \
      const int phys = btab[kv >> 4];                                           \
      const size_t gb = (((size_t)phys * HH + h) * BSZ + (kv & 15)) * DH + d4 * 4; \
      vreg[i][0] = *(const float4*)(vc + gb);                                   \
      vreg[i][1] = *(const float4*)(vc + gb + DH);                              \
    }                                                                           \
  }

  // convert prefetched fp32 -> bf16 and write LDS buffer BUF (waits vmcnt here)
#define STAGE_WRITE(BUF)                                                        \
  {                                                                             \
    _Pragma("unroll")                                                           \
    for (int i = 0; i < 2; ++i) {                                               \
      const int slot = i * 512 + tid;                                           \
      const int row = slot >> 4, c16 = slot & 15;                               \
      union { uint4 u4; unsigned u[4]; } w;                                     \
      w.u[0] = pk2(kreg[i][0].x, kreg[i][0].y);                                 \
      w.u[1] = pk2(kreg[i][0].z, kreg[i][0].w);                                 \
      w.u[2] = pk2(kreg[i][1].x, kreg[i][1].y);                                 \
      w.u[3] = pk2(kreg[i][1].z, kreg[i][1].w);                                 \
      *(uint4*)(kls[BUF] + c16 * 1024 + ((row ^ (c16 & 7)) << 4)) = w.u4;       \
    }                                                                           \
    _Pragma("unroll")                                                           \
    for (int i = 0; i < 2; ++i) {                                               \
      const int slot = i * 512 + tid;                                           \
      const int d4 = slot & 31, kvp = slot >> 5;                                \
      const float* aa = (const float*)&vreg[i][0];                              \
      const float* bp = (const float*)&vreg[i][1];                              \
      _Pragma("unroll")                                                         \
      for (int jj = 0; jj < 4; ++jj) {                                          \
        const int d = d4 * 4 + jj;                                              \
        const int vb = d * VROW + ((kvp * 4) ^ (((d >> 3) & 7) << 4));          \
        *(unsigned*)(vls[BUF] + vb) = pk2(aa[jj], bp[jj]);                      \
      }                                                                         \
    }                                                                           \
  }

  ISSUE_LOADS(t0 * KT)   // tile t0 in flight

  // ---- Q fragments (B-operand): lane = col q, provides Q[q][d = ks*16 + hi*8 + j] ----
  const float qscale = 0.08838834764831845f * 1.4426950408889634f;  // 1/sqrt(128)*log2(e)
  const int qbase = wave * 32;
  bf16x8 qf[8];
  {
    const float* qr = qg + ((size_t)bh * QLEN + qbase + ll) * DH;
#pragma unroll
    for (int ks = 0; ks < 8; ++ks) {
      const int d0 = ks * 16 + hi * 8;
      const float4 a  = *(const float4*)(qr + d0);
      const float4 bv = *(const float4*)(qr + d0 + 4);
      union { bf16x8 v; unsigned u[4]; } w;
      w.u[0] = pk2(a.x * qscale,  a.y * qscale);
      w.u[1] = pk2(a.z * qscale,  a.w * qscale);
      w.u[2] = pk2(bv.x * qscale, bv.y * qscale);
      w.u[3] = pk2(bv.z * qscale, bv.w * qscale);
      qf[ks] = w.v;
    }
  }

  f32x16 accT[4];   // O^T: lane q=qbase+ll, d = dt*32 + (reg&3) + 8*(reg>>2) + 4*hi
#pragma unroll
  for (int dt = 0; dt < 4; ++dt)
#pragma unroll
    for (int i = 0; i < 16; ++i) accT[dt][i] = 0.f;
  float mrow = -1e30f, lrow = 0.f;

  // ---- prologue: stage tile t0, prefetch t0+1 ----
  STAGE_WRITE(t0 & 1)
  if (t0 + 1 < t1) ISSUE_LOADS((t0 + 1) * KT)
  __syncthreads();

  for (int t = t0; t < t1; ++t) {
    const int kv0 = t * KT;
    const int bb  = t & 1;

    // ---- S^T = K · Q^T : chunk-major K reads (contiguous-permuted, conflict-free) ----
    f32x16 s[2];
#pragma unroll
    for (int i = 0; i < 16; ++i) { s[0][i] = 0.f; s[1][i] = 0.f; }
#pragma unroll
    for (int ks = 0; ks < 8; ++ks) {
      const int cch = 2 * ks + hi;
      const char* cb = kls[bb] + cch * 1024;
      const bf16x8 kf0 = *(const bf16x8*)(cb + (((ll)      ^ (cch & 7)) << 4));
      const bf16x8 kf1 = *(const bf16x8*)(cb + (((32 + ll) ^ (cch & 7)) << 4));
      s[0] = mfma32(kf0, qf[ks], s[0]);
      s[1] = mfma32(kf1, qf[ks], s[1]);
    }

    // ---- stage tile t+1 into the other buffer (write-late: lands well before barrier);
    //      convert VALU hides QK's MFMA latency into s[] ----
    if (t + 1 < t1) STAGE_WRITE(bb ^ 1)
    if (t + 2 < t1) ISSUE_LOADS((t + 2) * KT)

    // ---- online softmax: lane owns q-row; 32 scores, partner (lane^32) has other 32 ----
    if (kv0 + KT > seq) {
#pragma unroll
      for (int kvt = 0; kvt < 2; ++kvt)
#pragma unroll
        for (int r = 0; r < 16; ++r) {
          const int kvg = kv0 + kvt * 32 + (r & 3) + 8 * (r >> 2) + 4 * hi;
          if (kvg >= seq) s[kvt][r] = -1e30f;
        }
    }
    // tree max (dep depth ~5)
    float tm[16];
#pragma unroll
    for (int r = 0; r < 16; ++r) tm[r] = fmaxf(s[0][r], s[1][r]);
#pragma unroll
    for (int w2 = 8; w2 >= 1; w2 >>= 1)
#pragma unroll
      for (int r = 0; r < w2; ++r) tm[r] = fmaxf(tm[r], tm[r + w2]);
    float mx = fmaxf(tm[0], __shfl_xor(tm[0], 32));
    // T13 defer-max
    if (!__all(mx - mrow <= 8.0f)) {
      const float mnew  = fmaxf(mrow, mx);
      const float alpha = fexp2(mrow - mnew);
      mrow = mnew;
      lrow *= alpha;
#pragma unroll
      for (int dt = 0; dt < 4; ++dt)
#pragma unroll
        for (int i = 0; i < 16; ++i) accT[dt][i] *= alpha;
    }
#pragma unroll
    for (int kvt = 0; kvt < 2; ++kvt)
#pragma unroll
      for (int r = 0; r < 16; ++r)
        s[kvt][r] = fexp2(s[kvt][r] - mrow);   // bounded by 2^8
    // tree sum
    float ts[16];
#pragma unroll
    for (int r = 0; r < 16; ++r) ts[r] = s[0][r] + s[1][r];
#pragma unroll
    for (int w2 = 8; w2 >= 1; w2 >>= 1)
#pragma unroll
      for (int r = 0; r < w2; ++r) ts[r] += ts[r + w2];
    lrow += ts[0] + __shfl_xor(ts[0], 32);

    // ---- pack P (consecutive kv pairs: regs 2p,2p+1 -> kv k,k+1) ----
    unsigned pkk[2][8];
#pragma unroll
    for (int kvt = 0; kvt < 2; ++kvt)
#pragma unroll
      for (int p = 0; p < 8; ++p)
        pkk[kvt][p] = pk2(s[kvt][2 * p], s[kvt][2 * p + 1]);

    // ---- build P^T B-frags: cross-half exchange (lane <-> lane^32) ----
    bf16x8 pb[4];
#pragma unroll
    for (int kvb = 0; kvb < 4; ++kvb) {
      const int kvt = kvb >> 1;
      const int base = (kvb & 1) * 4;
      const unsigned send0 = hi ? pkk[kvt][base]     : pkk[kvt][base + 2];
      const unsigned send1 = hi ? pkk[kvt][base + 1] : pkk[kvt][base + 3];
      const unsigned recv0 = (unsigned)__shfl_xor((int)send0, 32);
      const unsigned recv1 = (unsigned)__shfl_xor((int)send1, 32);
      union { bf16x8 v; unsigned u[4]; } w;
      w.u[0] = hi ? recv0 : pkk[kvt][base];
      w.u[1] = hi ? recv1 : pkk[kvt][base + 1];
      w.u[2] = hi ? pkk[kvt][base + 2] : recv0;
      w.u[3] = hi ? pkk[kvt][base + 3] : recv1;
      pb[kvb] = w.v;
    }

    // ---- O^T += V^T · P^T : 4 d-tiles x 4 kv-blocks of 16 ----
#pragma unroll
    for (int dt = 0; dt < 4; ++dt) {
      const int d  = dt * 32 + ll;
      const int sw = ((d >> 3) & 7) << 4;
      const char* vbp = vls[bb] + d * VROW;
#pragma unroll
      for (int kvb = 0; kvb < 4; ++kvb) {
        const bf16x8 va = *(const bf16x8*)(vbp + ((kvb * 32 + hi * 16) ^ sw));
        accT[dt] = mfma32(va, pb[kvb], accT[dt]);
      }
    }

    __syncthreads();  // publish staged t+1; all waves done reading buf bb
  }

  // ---- epilogue: lane writes q-row qbase+ll; d = dt*32 + 8*r + 4*hi + 0..3 ----
  const int grow = bh * QLEN + qbase + ll;
  if (nkv == 1) {
    const float inv = 1.0f / lrow;
    float* orow = outd + (size_t)grow * DH;
#pragma unroll
    for (int dt = 0; dt < 4; ++dt)
#pragma unroll
      for (int r = 0; r < 4; ++r) {
        float4 v = make_float4(accT[dt][4 * r] * inv,     accT[dt][4 * r + 1] * inv,
                               accT[dt][4 * r + 2] * inv, accT[dt][4 * r + 3] * inv);
        *(float4*)(orow + dt * 32 + 8 * r + 4 * hi) = v;
      }
  } else {
    __hip_bfloat16* orow = opart + ((size_t)c * BHQ + grow) * DH;
#pragma unroll
    for (int dt = 0; dt < 4; ++dt)
#pragma unroll
      for (int r = 0; r < 4; ++r) {
        const unsigned lo2 = pk2(accT[dt][4 * r],     accT[dt][4 * r + 1]);
        const unsigned hi2 = pk2(accT[dt][4 * r + 2], accT[dt][4 * r + 3]);
        *(uint2*)((char*)orow + (dt * 32 + 8 * r + 4 * hi) * 2) = make_uint2(lo2, hi2);
      }
    if (hi == 0) {
      mpart[c * BHQ + grow] = mrow;
      lpart[c * BHQ + grow] = lrow;
    }
  }
}

__global__ void combine_kernel(const __hip_bfloat16* __restrict__ op,
                               const float* __restrict__ mp,
                               const float* __restrict__ lp,
                               float* __restrict__ out, int nkv) {
  const int idx = blockIdx.x * 256 + threadIdx.x;  // 8-elem group over BHQ*DH/8
  const int row = idx >> 4;                        // 16 groups per row (128/8)
  float M = -1e30f;
  for (int cc = 0; cc < nkv; ++cc) M = fmaxf(M, mp[cc * BHQ + row]);
  float den = 0.f;
  float o[8] = {0.f, 0.f, 0.f, 0.f, 0.f, 0.f, 0.f, 0.f};
  for (int cc = 0; cc < nkv; ++cc) {
    const float w = exp2f(mp[cc * BHQ + row] - M);
    den += lp[cc * BHQ + row] * w;
    const uint4 v = *(const uint4*)((const char*)op + ((size_t)cc * BHQ * DH + (size_t)idx * 8) * 2);
    const unsigned u[4] = {v.x, v.y, v.z, v.w};
#pragma unroll
    for (int j = 0; j < 4; ++j) {
      o[2 * j]     += w * bf2f((unsigned short)(u[j] & 0xffffu));
      o[2 * j + 1] += w * bf2f((unsigned short)(u[j] >> 16));
    }
  }
  const float inv = 1.0f / den;
  float4* dst = (float4*)(out + (size_t)idx * 8);
  dst[0] = make_float4(o[0] * inv, o[1] * inv, o[2] * inv, o[3] * inv);
  dst[1] = make_float4(o[4] * inv, o[5] * inv, o[6] * inv, o[7] * inv);
}

extern "C" void kernel_launch(void* const* d_in, const int* in_sizes, int n_in,
                              void* d_out, int out_size, void* d_ws, size_t ws_size,
                              hipStream_t stream) {
  const float* q  = (const float*)d_in[0];
  const float* kc = (const float*)d_in[1];
  const float* vc = (const float*)d_in[2];
  const int* bt   = (const int*)d_in[3];
  const int* sl   = (const int*)d_in[4];
  float* out = (float*)d_out;

  // per-chunk: bf16 O partial + fp32 m + fp32 l
  const size_t perchunk = (size_t)BHQ * DH * sizeof(__hip_bfloat16) + (size_t)BHQ * 2 * sizeof(float);
  int nkv = 1;
  if (ws_size >= 4 * perchunk) nkv = 4;        // 512 blocks: best measured (r5)
  else if (ws_size >= 2 * perchunk) nkv = 2;

  __hip_bfloat16* op = (__hip_bfloat16*)d_ws;
  float* mp = (float*)((char*)d_ws + (size_t)nkv * BHQ * DH * sizeof(__hip_bfloat16));
  float* lp = mp + (size_t)nkv * BHQ;

  paged_attn_kernel<<<dim3(BB * HH * nkv), dim3(512), 0, stream>>>(q, kc, vc, bt, sl, out, op, mp, lp, nkv);
  if (nkv > 1)
    combine_kernel<<<dim3(BHQ * DH / 8 / 256), dim3(256), 0, stream>>>(op, mp, lp, out, nkv);
}